// Round 1
// 701.549 us; speedup vs baseline: 2.2348x; 2.2348x over previous
//
#include <hip/hip_runtime.h>

// LSTM forward: B=65536, T=20, I=36, H=30. Gate order i,f,g,o.
// Inputs (fp32): x[B,T,I], W_ih[4H,I], W_hh[4H,H], b_ih[4H], b_hh[4H]
// Output (fp32, concat): out[B,T,H], h_n[1,B,H], c_n[1,B,H]
//
// R4 restructure: occupancy was the bottleneck (1 wave/SIMD, VALUBusy 28%).
// Now 4 waves per 64 batch elements — wave w computes gate w's 30 rows
// (weight pointers stay wave-uniform -> scalar loads), exchange activated
// gate values through LDS G[120][64] (lane-minor: conflict-free), and every
// wave redundantly keeps h,c in registers (combine is cheap; avoids an
// h-broadcast round-trip). 1024 blocks = 4 blocks/CU = 16 waves/CU.

constexpr int BB = 65536;
constexpr int TT = 20;
constexpr int II = 36;
constexpr int HH = 30;

__device__ __forceinline__ float fast_sigmoid(float v) {
    float e = __expf(-v);                      // v_exp_f32
    return __builtin_amdgcn_rcpf(1.f + e);     // v_rcp_f32
}
__device__ __forceinline__ float fast_tanh(float v) {
    // 1 - 2/(exp(2v)+1): saturates to +/-1, no inf/inf NaN
    float e = __expf(2.f * v);
    return 1.f - 2.f * __builtin_amdgcn_rcpf(e + 1.f);
}

__global__ __launch_bounds__(256, 4) void lstm_fwd(
    const float* __restrict__ x,
    const float* __restrict__ Wih,   // [4H][II] row-major, gate rows i,f,g,o
    const float* __restrict__ Whh,   // [4H][HH]
    const float* __restrict__ bih,   // [4H]
    const float* __restrict__ bhh,   // [4H]
    float* __restrict__ out) {

    __shared__ float G[4 * HH][64];  // [gate row][elem] activated gate values

    const int lane = threadIdx.x & 63;
    const int w = __builtin_amdgcn_readfirstlane((int)(threadIdx.x >> 6)); // gate/role 0..3
    const int b = blockIdx.x * 64 + lane;

    const float* xrow = x + (size_t)b * TT * II;
    float* orow = out + (size_t)b * TT * HH;

    // wave-uniform bases for this role's 30 gate rows -> s_load path
    const float* wihBase = Wih + (size_t)(HH * w) * II;
    const float* whhBase = Whh + (size_t)(HH * w) * HH;
    const float* bihBase = bih + HH * w;
    const float* bhhBase = bhh + HH * w;

    float h[HH], c[HH];
#pragma unroll
    for (int n = 0; n < HH; n++) { h[n] = 0.f; c[n] = 0.f; }

#pragma unroll 1
    for (int t = 0; t < TT; t++) {
        // x row for this timestep: 36 fp32 = 144 B, 16B-aligned (b*2880 + t*144).
        // All 4 waves of the block load the same 64 rows; L1 serves 3 of 4.
        float xr[II];
        const float4* xv = (const float4*)(xrow + t * II);
#pragma unroll
        for (int q = 0; q < II / 4; q++) {
            float4 u = xv[q];
            xr[4 * q + 0] = u.x;
            xr[4 * q + 1] = u.y;
            xr[4 * q + 2] = u.z;
            xr[4 * q + 3] = u.w;
        }

        // phase 1: this role's 30 gate pre-activations (dual indep FMA chains
        // per row, unroll 2 -> 4 chains to cover 4-cyc dependent latency)
#pragma unroll 2
        for (int n = 0; n < HH; n++) {
            const float* wi = wihBase + n * II;   // wave-uniform
            const float* wh = whhBase + n * HH;   // wave-uniform
            float a0 = bihBase[n] + bhhBase[n];
            float a1 = 0.f;
#pragma unroll
            for (int k = 0; k < II; k++) a0 += wi[k] * xr[k];
#pragma unroll
            for (int k = 0; k < HH; k++) a1 += wh[k] * h[k];
            float a = a0 + a1;
            float v = (w == 2) ? fast_tanh(a) : fast_sigmoid(a);  // uniform branch
            G[HH * w + n][lane] = v;              // lane-minor: conflict-free
        }
        __syncthreads();

        // phase 2: every wave redundantly combines -> h,c stay in registers
#pragma unroll
        for (int n = 0; n < HH; n++) {
            float it = G[n][lane];
            float ft = G[HH + n][lane];
            float gt = G[2 * HH + n][lane];
            float ot = G[3 * HH + n][lane];
            float cn = ft * c[n] + it * gt;
            c[n] = cn;
            h[n] = ot * fast_tanh(cn);
        }
        __syncthreads();  // protect G before next timestep's writes

        // store h_t (role 0 only; static indices, fire-and-forget)
        if (w == 0) {
            float2* op = (float2*)(orow + t * HH);  // 8B-aligned (b*2400+t*120)
#pragma unroll
            for (int q = 0; q < HH / 2; q++)
                op[q] = make_float2(h[2 * q], h[2 * q + 1]);
        }
    }

    if (w == 0) {
        float* hN = out + (size_t)BB * TT * HH + (size_t)b * HH;
        float* cN = out + (size_t)BB * TT * HH + (size_t)BB * HH + (size_t)b * HH;
        float2* hp = (float2*)hN;
        float2* cp = (float2*)cN;
#pragma unroll
        for (int q = 0; q < HH / 2; q++) {
            hp[q] = make_float2(h[2 * q], h[2 * q + 1]);
            cp[q] = make_float2(c[2 * q], c[2 * q + 1]);
        }
    }
}

extern "C" void kernel_launch(void* const* d_in, const int* in_sizes, int n_in,
                              void* d_out, int out_size, void* d_ws, size_t ws_size,
                              hipStream_t stream) {
    const float* x    = (const float*)d_in[0];
    const float* w_ih = (const float*)d_in[1];
    const float* w_hh = (const float*)d_in[2];
    const float* b_ih = (const float*)d_in[3];
    const float* b_hh = (const float*)d_in[4];
    float* out = (float*)d_out;

    hipLaunchKernelGGL(lstm_fwd, dim3(BB / 64), dim3(256), 0, stream,
                       x, w_ih, w_hh, b_ih, b_hh, out);
}